// Round 1
// baseline (1667.149 us; speedup 1.0000x reference)
//
#include <hip/hip_runtime.h>
#include <stdint.h>

#define HW_   4225
#define NPIX_ 16900
#define NC_   19
#define QL_   2975
#define EPSF  1e-5f

typedef __bf16 bf16x8 __attribute__((ext_vector_type(8)));
typedef float  f32x4  __attribute__((ext_vector_type(4)));

__device__ __forceinline__ unsigned short f2bf(float f) {
    union { float f; unsigned u; } v; v.f = f;
    unsigned u = v.u;
    return (unsigned short)((u + 0x7fffu + ((u >> 16) & 1u)) >> 16);
}
__device__ __forceinline__ float bf2f(unsigned short b) {
    union { unsigned u; float f; } v; v.u = ((unsigned)b) << 16;
    return v.f;
}

// ---------------- transpose x: (B,2048,65,65) f32 -> (B,4225,2048) bf16 ----------------
__global__ void k_transpose_x(const float* __restrict__ x, unsigned short* __restrict__ xt) {
    __shared__ unsigned short T[64][66];
    int b  = blockIdx.z;
    int c0 = blockIdx.y * 64;
    int p0 = blockIdx.x * 64;
    int tx = threadIdx.x & 63, ty = threadIdx.x >> 6;
    if (p0 + tx < HW_) {
        #pragma unroll
        for (int i = 0; i < 16; ++i) {
            int cl = i * 4 + ty;
            T[cl][tx] = f2bf(x[((size_t)(b * 2048 + c0 + cl)) * HW_ + p0 + tx]);
        }
    }
    __syncthreads();
    #pragma unroll
    for (int i = 0; i < 16; ++i) {
        int pl = i * 4 + ty;
        int p = p0 + pl;
        if (p < HW_) xt[((size_t)(b * HW_ + p)) * 2048 + c0 + tx] = T[tx][pl];
    }
}

// ---------------- global average pool: gp[b][c] ----------------
__global__ void k_gp(const float* __restrict__ x, float* __restrict__ gp) {
    int wid  = blockIdx.x * 4 + (threadIdx.x >> 6);
    int lane = threadIdx.x & 63;
    int b = wid >> 11, c = wid & 2047;
    const float* src = x + (size_t)(b * 2048 + c) * HW_;
    float s = 0.f;
    for (int i = lane; i < HW_; i += 64) s += src[i];
    #pragma unroll
    for (int off = 32; off; off >>= 1) s += __shfl_down(s, off);
    if (lane == 0) gp[b * 2048 + c] = s * (1.0f / HW_);
}

// ---------------- weight reorder: (co,ci,taps) f32 -> (tap,co,ci) bf16 ----------------
__global__ void k_wreorder(const float* __restrict__ src, unsigned short* __restrict__ dst,
                           int ci_n, int ntaps) {
    int ci  = blockIdx.x * 256 + threadIdx.x;
    int co  = blockIdx.y, tap = blockIdx.z;
    dst[((size_t)tap * 256 + co) * ci_n + ci] =
        f2bf(src[((size_t)co * ci_n + ci) * ntaps + tap]);
}

// ---------------- implicit-GEMM conv, 128x128 tile, bf16 MFMA 16x16x32 ----------------
__global__ __launch_bounds__(256) void k_conv_gemm(
    const unsigned short* __restrict__ xin, const unsigned short* __restrict__ wr_base,
    unsigned short* __restrict__ out, int cin, int ostride, int is_head)
{
    __shared__ unsigned short As[128 * 72];
    __shared__ unsigned short Bs[128 * 72];
    const int tid = threadIdx.x;
    const int bz = blockIdx.z;
    int dil, ntaps, coff;
    if (is_head) { dil = 1; ntaps = 9; coff = 0; }
    else         { dil = 12 * bz; ntaps = bz ? 9 : 1; coff = 256 * (bz + 1); }
    const int mbase = blockIdx.x * 128;
    const int nbase = blockIdx.y * 128;

    const int srow = tid >> 1;
    const int scol = (tid & 1) << 5;   // 0 or 32 elements

    const int pix = mbase + srow;
    const int pb = pix / HW_;
    const int pr = pix - pb * HW_;
    const int py = pr / 65;
    const int px = pr - py * 65;

    f32x4 acc[4][4];
    #pragma unroll
    for (int i = 0; i < 4; ++i)
        #pragma unroll
        for (int j = 0; j < 4; ++j) acc[i][j] = (f32x4){0.f, 0.f, 0.f, 0.f};

    const int wv = tid >> 6, lane = tid & 63;
    const int wm = wv >> 1, wn = wv & 1;
    const int quad = lane >> 4, lrow = lane & 15;

    for (int tap = 0; tap < ntaps; ++tap) {
        int dy = (ntaps == 1) ? 0 : (tap / 3 - 1) * dil;
        int dx = (ntaps == 1) ? 0 : (tap % 3 - 1) * dil;
        int ys = py + dy, xs = px + dx;
        bool valid = (pix < NPIX_) && ((unsigned)ys < 65u) && ((unsigned)xs < 65u);
        size_t aoff = valid ? ((size_t)(pb * HW_ + ys * 65 + xs) * cin + scol) : 0;
        const unsigned short* asrc = xin + aoff;
        const unsigned short* bsrc = wr_base +
            ((size_t)(bz * 9 + tap) * 256 + (nbase + srow)) * cin + scol;

        for (int kc = 0; kc < cin; kc += 64) {
            uint4 a0, a1, a2, a3;
            if (valid) {
                const uint4* ap = (const uint4*)(asrc + kc);
                a0 = ap[0]; a1 = ap[1]; a2 = ap[2]; a3 = ap[3];
            } else {
                a0 = a1 = a2 = a3 = make_uint4(0u, 0u, 0u, 0u);
            }
            const uint4* bp = (const uint4*)(bsrc + kc);
            uint4 b0 = bp[0], b1 = bp[1], b2 = bp[2], b3 = bp[3];
            __syncthreads();   // WAR: previous iteration's LDS reads done
            uint4* ad = (uint4*)(As + srow * 72 + scol);
            ad[0] = a0; ad[1] = a1; ad[2] = a2; ad[3] = a3;
            uint4* bd = (uint4*)(Bs + srow * 72 + scol);
            bd[0] = b0; bd[1] = b1; bd[2] = b2; bd[3] = b3;
            __syncthreads();

            #pragma unroll
            for (int kk = 0; kk < 64; kk += 32) {
                const int ko = kk + (quad << 3);
                bf16x8 af[4], bfv[4];
                #pragma unroll
                for (int i = 0; i < 4; ++i)
                    af[i] = *(const bf16x8*)(As + (wm * 64 + i * 16 + lrow) * 72 + ko);
                #pragma unroll
                for (int j = 0; j < 4; ++j)
                    bfv[j] = *(const bf16x8*)(Bs + (wn * 64 + j * 16 + lrow) * 72 + ko);
                #pragma unroll
                for (int i = 0; i < 4; ++i)
                    #pragma unroll
                    for (int j = 0; j < 4; ++j)
                        acc[i][j] = __builtin_amdgcn_mfma_f32_16x16x32_bf16(
                            af[i], bfv[j], acc[i][j], 0, 0, 0);
            }
        }
    }

    #pragma unroll
    for (int i = 0; i < 4; ++i) {
        int prow = mbase + wm * 64 + i * 16 + quad * 4;
        #pragma unroll
        for (int r = 0; r < 4; ++r) {
            int p = prow + r;
            if (p < NPIX_) {
                unsigned short* orow = out + (size_t)p * ostride + coff + nbase + wn * 64 + lrow;
                #pragma unroll
                for (int j = 0; j < 4; ++j) orow[j * 16] = f2bf(acc[i][j][r]);
            }
        }
    }
}

// ---------------- per-channel sum/sumsq over all pixels (atomic partials) ----------------
__global__ void k_stats(const unsigned short* __restrict__ buf, int stride, int coff,
                        float* __restrict__ sums, float* __restrict__ sumsq) {
    int c = blockIdx.y * 256 + threadIdx.x;
    int p0 = blockIdx.x * 130, p1 = p0 + 130;
    float s = 0.f, q = 0.f;
    for (int p = p0; p < p1; ++p) {
        float v = bf2f(buf[(size_t)p * stride + coff + c]);
        s += v; q += v * v;
    }
    atomicAdd(&sums[c], s);
    atomicAdd(&sumsq[c], q);
}

// ---------------- br0: (w_gp @ gp) -> pre-BN (4,256) ----------------
__global__ void k_br0mv(const float* __restrict__ gp, const float* __restrict__ wgp,
                        float* __restrict__ pre) {
    __shared__ float red[256];
    int co = blockIdx.x, t = threadIdx.x;
    float s0 = 0, s1 = 0, s2 = 0, s3 = 0;
    for (int ci = t; ci < 2048; ci += 256) {
        float w = wgp[(size_t)co * 2048 + ci];
        s0 += w * gp[ci];        s1 += w * gp[2048 + ci];
        s2 += w * gp[4096 + ci]; s3 += w * gp[6144 + ci];
    }
    #pragma unroll
    for (int b = 0; b < 4; ++b) {
        float s = (b == 0) ? s0 : (b == 1) ? s1 : (b == 2) ? s2 : s3;
        red[t] = s; __syncthreads();
        for (int st = 128; st; st >>= 1) { if (t < st) red[t] += red[t + st]; __syncthreads(); }
        if (t == 0) pre[b * 256 + co] = red[0];
        __syncthreads();
    }
}

// ---------------- br0 BN over batch-of-4 + relu ----------------
__global__ void k_br0bn(const float* __restrict__ pre, const float* __restrict__ g,
                        const float* __restrict__ bb, float* __restrict__ post) {
    int t = threadIdx.x;
    float v0 = pre[t], v1 = pre[256 + t], v2 = pre[512 + t], v3 = pre[768 + t];
    float m = 0.25f * (v0 + v1 + v2 + v3);
    float var = 0.25f * (v0 * v0 + v1 * v1 + v2 * v2 + v3 * v3) - m * m;
    float sc = g[t] * rsqrtf(var + EPSF), sh = bb[t] - m * sc;
    post[t]       = fmaxf(v0 * sc + sh, 0.f);
    post[256 + t] = fmaxf(v1 * sc + sh, 0.f);
    post[512 + t] = fmaxf(v2 * sc + sh, 0.f);
    post[768 + t] = fmaxf(v3 * sc + sh, 0.f);
}

// ---------------- normalize ASPP (in-place) + broadcast br0 into channels 0..255 --------
__global__ void k_norm_aspp(unsigned short* __restrict__ buf,
                            const float* __restrict__ sums, const float* __restrict__ sumsq,
                            const float* __restrict__ g1, const float* __restrict__ b1,
                            const float* __restrict__ g2, const float* __restrict__ b2,
                            const float* __restrict__ g3, const float* __restrict__ b3,
                            const float* __restrict__ g4, const float* __restrict__ b4,
                            const float* __restrict__ br0) {
    int cg = blockIdx.y, t = threadIdx.x;
    int p0 = blockIdx.x * 130, p1 = p0 + 130;
    if (cg == 0) {
        for (int p = p0; p < p1; ++p) {
            int b = p / HW_;
            buf[(size_t)p * 1280 + t] = f2bf(br0[b * 256 + t]);
        }
    } else {
        int c = (cg - 1) * 256 + t;
        float m = sums[c] * (1.f / NPIX_);
        float var = sumsq[c] * (1.f / NPIX_) - m * m;
        const float* g  = (cg == 1) ? g1 : (cg == 2) ? g2 : (cg == 3) ? g3 : g4;
        const float* bb = (cg == 1) ? b1 : (cg == 2) ? b2 : (cg == 3) ? b3 : b4;
        float sc = g[t] * rsqrtf(var + EPSF), sh = bb[t] - m * sc;
        for (int p = p0; p < p1; ++p) {
            size_t idx = (size_t)p * 1280 + cg * 256 + t;
            float v = bf2f(buf[idx]) * sc + sh;
            buf[idx] = f2bf(fmaxf(v, 0.f));
        }
    }
}

// ---------------- normalize head (in-place) -> fea ----------------
__global__ void k_norm_head(unsigned short* __restrict__ buf,
                            const float* __restrict__ sums, const float* __restrict__ sumsq,
                            const float* __restrict__ g, const float* __restrict__ bb) {
    int t = threadIdx.x;
    float m = sums[t] * (1.f / NPIX_);
    float var = sumsq[t] * (1.f / NPIX_) - m * m;
    float sc = g[t] * rsqrtf(var + EPSF), sh = bb[t] - m * sc;
    int p0 = blockIdx.x * 130, p1 = p0 + 130;
    for (int p = p0; p < p1; ++p) {
        size_t idx = (size_t)p * 256 + t;
        float v = bf2f(buf[idx]) * sc + sh;
        buf[idx] = f2bf(fmaxf(v, 0.f));
    }
}

// ---------------- final 1x1: res (NCHW into d_out) ----------------
__global__ void k_final(const unsigned short* __restrict__ fea, const float* __restrict__ wfin,
                        const float* __restrict__ bfin, float* __restrict__ outres) {
    int idx = blockIdx.x * 256 + threadIdx.x;
    if (idx >= NPIX_ * NC_) return;
    int p = idx / NC_, k = idx - p * NC_;
    const unsigned short* f = fea + (size_t)p * 256;
    const float* w = wfin + k * 256;
    float acc = 0.f;
    for (int c = 0; c < 256; c += 8) {
        uint4 q = *(const uint4*)(f + c);
        unsigned u0 = q.x, u1 = q.y, u2 = q.z, u3 = q.w;
        acc += bf2f((unsigned short)(u0 & 0xffff)) * w[c + 0];
        acc += bf2f((unsigned short)(u0 >> 16))    * w[c + 1];
        acc += bf2f((unsigned short)(u1 & 0xffff)) * w[c + 2];
        acc += bf2f((unsigned short)(u1 >> 16))    * w[c + 3];
        acc += bf2f((unsigned short)(u2 & 0xffff)) * w[c + 4];
        acc += bf2f((unsigned short)(u2 >> 16))    * w[c + 5];
        acc += bf2f((unsigned short)(u3 & 0xffff)) * w[c + 6];
        acc += bf2f((unsigned short)(u3 >> 16))    * w[c + 7];
    }
    acc += bfin[k];
    int b = p / HW_, yx = p - b * HW_;
    outres[(size_t)(b * NC_ + k) * HW_ + yx] = acc;
}

// ---------------- argmax over classes (first-max) ----------------
__global__ void k_argmax(const float* __restrict__ res, int* __restrict__ pred) {
    int p = blockIdx.x * 256 + threadIdx.x;
    if (p >= NPIX_) return;
    int b = p / HW_, yx = p - b * HW_;
    const float* r = res + (size_t)b * NC_ * HW_ + yx;
    float best = r[0]; int bi = 0;
    #pragma unroll
    for (int k = 1; k < NC_; ++k) {
        float v = r[(size_t)k * HW_];
        if (v > best) { best = v; bi = k; }
    }
    pred[p] = bi;
}

// ---------------- per-class masked sums of fea + counts ----------------
__global__ void k_keysums(const unsigned short* __restrict__ fea, const int* __restrict__ pred,
                          float* __restrict__ sums, float* __restrict__ counts) {
    __shared__ float acc[256 * NC_];
    __shared__ float cnt[NC_];
    int t = threadIdx.x;
    #pragma unroll
    for (int k = 0; k < NC_; ++k) acc[t * NC_ + k] = 0.f;
    if (t < NC_) cnt[t] = 0.f;
    __syncthreads();
    int p0 = blockIdx.x * 130, p1 = p0 + 130;
    for (int p = p0; p < p1; ++p) {
        int k = pred[p];
        float v = bf2f(fea[(size_t)p * 256 + t]);
        acc[t * NC_ + k] += v;
        if (t == 0) cnt[k] += 1.f;
    }
    __syncthreads();
    #pragma unroll
    for (int k = 0; k < NC_; ++k) atomicAdd(&sums[k * 256 + t], acc[t * NC_ + k]);
    if (t < NC_) atomicAdd(&counts[t], cnt[t]);
}

// ---------------- keys: divide by counts, L2-normalize ----------------
__global__ void k_keys(const float* __restrict__ sums, const float* __restrict__ counts,
                       float* __restrict__ keys) {
    __shared__ float red[256];
    int t = threadIdx.x;
    for (int k = 0; k < NC_; ++k) {
        float v = sums[k * 256 + t] / fmaxf(counts[k], 1.f);
        red[t] = v * v; __syncthreads();
        for (int s = 128; s; s >>= 1) { if (t < s) red[t] += red[t + s]; __syncthreads(); }
        float inv = 1.f / fmaxf(sqrtf(red[0]), 1e-12f);
        keys[k * 256 + t] = v * inv;
        __syncthreads();
    }
}

// ---------------- sims: Sexp[k][j] = sum_l exp(a), pos_a for diagonal ----------------
__global__ void k_sims(const float* __restrict__ keys, const float* __restrict__ queues,
                       float* __restrict__ Sexp, float* __restrict__ pos_a) {
    __shared__ float kl[NC_ * 256];
    __shared__ float red[256];
    int t = threadIdx.x;
    int j = blockIdx.x, lc = blockIdx.y;
    #pragma unroll
    for (int k = 0; k < NC_; ++k) kl[k * 256 + t] = keys[k * 256 + t];
    __syncthreads();
    int l = lc * 256 + t;
    bool lv = l < QL_;
    float a[NC_];
    #pragma unroll
    for (int k = 0; k < NC_; ++k) a[k] = 0.f;
    if (lv) {
        const float* q = queues + (size_t)j * 256 * QL_ + l;
        for (int c = 0; c < 256; ++c) {
            float qv = q[(size_t)c * QL_];
            #pragma unroll
            for (int k = 0; k < NC_; ++k) a[k] += kl[k * 256 + c] * qv;
        }
    }
    const float invt = 1.f / (256.f * 0.2f);
    if (lv) pos_a[j * QL_ + l] = a[j] * invt;
    for (int k = 0; k < NC_; ++k) {
        float e = lv ? __expf(a[k] * invt) : 0.f;
        red[t] = e; __syncthreads();
        for (int s = 128; s; s >>= 1) { if (t < s) red[t] += red[t + s]; __syncthreads(); }
        if (t == 0) atomicAdd(&Sexp[k * NC_ + j], red[0]);
        __syncthreads();
    }
}

// ---------------- final loss ----------------
__global__ void k_loss(const float* __restrict__ Sexp, const float* __restrict__ pos_a,
                       const float* __restrict__ counts, float* __restrict__ out_loss) {
    __shared__ float red[256];
    __shared__ float lseneg[NC_];
    int t = threadIdx.x;
    if (t < NC_) {
        float s = 0.f;
        for (int j = 0; j < NC_; ++j) if (j != t) s += Sexp[t * NC_ + j];
        lseneg[t] = logf(s);
    }
    __syncthreads();
    float total = 0.f;
    for (int k = 0; k < NC_; ++k) {
        float L = lseneg[k];
        float s = 0.f;
        for (int l = t; l < QL_; l += 256) {
            float pos = pos_a[k * QL_ + l];
            float m = fmaxf(pos, L);
            s += logf(__expf(pos - m) + __expf(L - m)) + m - pos;
        }
        red[t] = s; __syncthreads();
        for (int st = 128; st; st >>= 1) { if (t < st) red[t] += red[t + st]; __syncthreads(); }
        if (t == 0 && counts[k] > 0.f) total += red[0] * (1.f / QL_);
        __syncthreads();
    }
    if (t == 0) *out_loss = total;
}

extern "C" void kernel_launch(void* const* d_in, const int* in_sizes, int n_in,
                              void* d_out, int out_size, void* d_ws, size_t ws_size,
                              hipStream_t stream) {
    const float* x      = (const float*)d_in[0];
    const float* w_gp   = (const float*)d_in[1];
    const float* g_gp   = (const float*)d_in[2];
    const float* b_gp   = (const float*)d_in[3];
    const float* w_1x1  = (const float*)d_in[4];
    const float* g_1x1  = (const float*)d_in[5];
    const float* b_1x1  = (const float*)d_in[6];
    const float* w_d12  = (const float*)d_in[7];
    const float* g_d12  = (const float*)d_in[8];
    const float* b_d12  = (const float*)d_in[9];
    const float* w_d24  = (const float*)d_in[10];
    const float* g_d24  = (const float*)d_in[11];
    const float* b_d24  = (const float*)d_in[12];
    const float* w_d36  = (const float*)d_in[13];
    const float* g_d36  = (const float*)d_in[14];
    const float* b_d36  = (const float*)d_in[15];
    const float* w_head = (const float*)d_in[16];
    const float* g_head = (const float*)d_in[17];
    const float* b_head = (const float*)d_in[18];
    const float* w_fin  = (const float*)d_in[19];
    const float* b_fin  = (const float*)d_in[20];
    const float* queues = (const float*)d_in[21];

    char* ws = (char*)d_ws;
    size_t off = 0;
    auto alloc = [&](size_t bytes) { void* p = ws + off; off += (bytes + 255) & ~(size_t)255; return p; };

    unsigned short* x_t     = (unsigned short*)alloc((size_t)4 * HW_ * 2048 * 2);   // 69.2 MB
    unsigned short* wr_aspp = (unsigned short*)alloc((size_t)4 * 9 * 256 * 2048 * 2); // 37.7 MB
    unsigned short* wr_head = (unsigned short*)alloc((size_t)9 * 256 * 1280 * 2);   // 5.9 MB
    unsigned short* aspp    = (unsigned short*)alloc((size_t)NPIX_ * 1280 * 2);     // 43.3 MB
    unsigned short* headb   = (unsigned short*)alloc((size_t)NPIX_ * 256 * 2);      // 8.7 MB
    float* gp      = (float*)alloc(8192 * 4);
    float* br0pre  = (float*)alloc(1024 * 4);
    float* br0post = (float*)alloc(1024 * 4);
    int*   pred    = (int*)alloc((size_t)NPIX_ * 4);
    float* pos_a   = (float*)alloc((size_t)NC_ * QL_ * 4);
    // zeroed accumulators (contiguous)
    float* zbase      = (float*)alloc(7808 * 4);
    float* aspp_sums  = zbase;            // 1024
    float* aspp_sumsq = zbase + 1024;     // 1024
    float* head_sums  = zbase + 2048;     // 256
    float* head_sumsq = zbase + 2304;     // 256
    float* key_sums   = zbase + 2560;     // 19*256 = 4864
    float* counts     = zbase + 7424;     // 19
    float* Sexp       = zbase + 7443;     // 361
    (void)ws_size; (void)in_sizes; (void)n_in; (void)out_size;

    float* res  = (float*)d_out;
    float* loss = (float*)d_out + (size_t)NPIX_ * NC_;

    hipMemsetAsync(zbase, 0, 7808 * 4, stream);

    k_transpose_x<<<dim3(67, 32, 4), 256, 0, stream>>>(x, x_t);
    k_gp<<<2048, 256, 0, stream>>>(x, gp);

    // weight reorders: branch slots of wr_aspp are [branch][9][256][cin]
    k_wreorder<<<dim3(8, 256, 1), 256, 0, stream>>>(w_1x1, wr_aspp, 2048, 1);
    k_wreorder<<<dim3(8, 256, 9), 256, 0, stream>>>(w_d12, wr_aspp + (size_t)1 * 9 * 256 * 2048, 2048, 9);
    k_wreorder<<<dim3(8, 256, 9), 256, 0, stream>>>(w_d24, wr_aspp + (size_t)2 * 9 * 256 * 2048, 2048, 9);
    k_wreorder<<<dim3(8, 256, 9), 256, 0, stream>>>(w_d36, wr_aspp + (size_t)3 * 9 * 256 * 2048, 2048, 9);
    k_wreorder<<<dim3(5, 256, 9), 256, 0, stream>>>(w_head, wr_head, 1280, 9);

    // ASPP convs (branch = blockIdx.z): 1x1, d12, d24, d36 -> aspp channels 256..1279
    k_conv_gemm<<<dim3(133, 2, 4), 256, 0, stream>>>(x_t, wr_aspp, aspp, 2048, 1280, 0);

    k_stats<<<dim3(130, 4), 256, 0, stream>>>(aspp, 1280, 256, aspp_sums, aspp_sumsq);
    k_br0mv<<<256, 256, 0, stream>>>(gp, w_gp, br0pre);
    k_br0bn<<<1, 256, 0, stream>>>(br0pre, g_gp, b_gp, br0post);
    k_norm_aspp<<<dim3(130, 5), 256, 0, stream>>>(aspp, aspp_sums, aspp_sumsq,
        g_1x1, b_1x1, g_d12, b_d12, g_d24, b_d24, g_d36, b_d36, br0post);

    // head conv (1280 -> 256)
    k_conv_gemm<<<dim3(133, 2, 1), 256, 0, stream>>>(aspp, wr_head, headb, 1280, 256, 1);
    k_stats<<<dim3(130, 1), 256, 0, stream>>>(headb, 256, 0, head_sums, head_sumsq);
    k_norm_head<<<130, 256, 0, stream>>>(headb, head_sums, head_sumsq, g_head, b_head);

    // final 1x1 -> res (d_out, NCHW), argmax, region keys, contrast loss
    k_final<<<(NPIX_ * NC_ + 255) / 256, 256, 0, stream>>>(headb, w_fin, b_fin, res);
    k_argmax<<<(NPIX_ + 255) / 256, 256, 0, stream>>>(res, pred);
    k_keysums<<<130, 256, 0, stream>>>(headb, pred, key_sums, counts);
    k_keys<<<1, 256, 0, stream>>>(key_sums, counts, (float*)br0pre /*reuse as keys*/);
    k_sims<<<dim3(NC_, 12), 256, 0, stream>>>((float*)br0pre, queues, Sexp, pos_a);
    k_loss<<<1, 256, 0, stream>>>(Sexp, pos_a, counts, loss);
}

// Round 2
// 1405.468 us; speedup vs baseline: 1.1862x; 1.1862x over previous
//
#include <hip/hip_runtime.h>
#include <stdint.h>

#define HW_   4225
#define NPIX_ 16900
#define NC_   19
#define QL_   2975
#define EPSF  1e-5f

#define AS1 __attribute__((address_space(1)))
#define AS3 __attribute__((address_space(3)))

typedef __bf16 bf16x8 __attribute__((ext_vector_type(8)));
typedef float  f32x4  __attribute__((ext_vector_type(4)));

__device__ __forceinline__ unsigned short f2bf(float f) {
    union { float f; unsigned u; } v; v.f = f;
    unsigned u = v.u;
    return (unsigned short)((u + 0x7fffu + ((u >> 16) & 1u)) >> 16);
}
__device__ __forceinline__ float bf2f(unsigned short b) {
    union { unsigned u; float f; } v; v.u = ((unsigned)b) << 16;
    return v.f;
}

// ------- transpose x: (B,2048,65,65) f32 -> (B,4225,2048) bf16, fused gp sums -------
__global__ void k_transpose_x(const float* __restrict__ x, unsigned short* __restrict__ xt,
                              float* __restrict__ gp_acc) {
    __shared__ float T[64][66];
    __shared__ float red[256];
    int b  = blockIdx.z;
    int c0 = blockIdx.y * 64;
    int p0 = blockIdx.x * 64;
    int tx = threadIdx.x & 63, ty = threadIdx.x >> 6;
    bool pv = (p0 + tx) < HW_;
    #pragma unroll
    for (int i = 0; i < 16; ++i) {
        int cl = i * 4 + ty;
        T[cl][tx] = pv ? x[((size_t)(b * 2048 + c0 + cl)) * HW_ + p0 + tx] : 0.f;
    }
    __syncthreads();
    #pragma unroll
    for (int i = 0; i < 16; ++i) {
        int pl = i * 4 + ty;
        int p = p0 + pl;
        if (p < HW_) xt[((size_t)(b * HW_ + p)) * 2048 + c0 + tx] = f2bf(T[tx][pl]);
    }
    // per-channel partial sums (channel = tx)
    float s = 0.f;
    #pragma unroll
    for (int k = 0; k < 16; ++k) s += T[tx][ty * 16 + k];
    red[threadIdx.x] = s;
    __syncthreads();
    if (threadIdx.x < 64) {
        float t = red[threadIdx.x] + red[64 + threadIdx.x] + red[128 + threadIdx.x] + red[192 + threadIdx.x];
        atomicAdd(&gp_acc[b * 2048 + c0 + threadIdx.x], t);
    }
}

// ---------------- weight reorder: (co,ci,taps) f32 -> (tap,co,ci) bf16 ----------------
__global__ void k_wreorder(const float* __restrict__ src, unsigned short* __restrict__ dst,
                           int ci_n, int ntaps) {
    int ci  = blockIdx.x * 256 + threadIdx.x;
    int co  = blockIdx.y, tap = blockIdx.z;
    dst[((size_t)tap * 256 + co) * ci_n + ci] =
        f2bf(src[((size_t)co * ci_n + ci) * ntaps + tap]);
}

// ------- implicit-GEMM conv, 128x128 tile, global_load_lds staging, XOR swizzle -------
__global__ __launch_bounds__(256) void k_conv_gemm(
    const unsigned short* __restrict__ xin, const unsigned short* __restrict__ wr_base,
    unsigned short* __restrict__ out, const unsigned short* __restrict__ zp,
    int cin, int ostride, int is_head)
{
    __shared__ unsigned short As[128 * 64];
    __shared__ unsigned short Bs[128 * 64];
    __shared__ int tapvalid;
    const int tid = threadIdx.x;
    const int bz = blockIdx.z;
    int dil, ntaps, coff;
    if (is_head) { dil = 1; ntaps = 9; coff = 0; }
    else         { dil = 12 * bz; ntaps = bz ? 9 : 1; coff = 256 * (bz + 1); }
    const int mbase = blockIdx.x * 128;
    const int nbase = blockIdx.y * 128;

    const int wv = tid >> 6, lane = tid & 63;
    const int wm = wv >> 1, wn = wv & 1;
    const int quad = lane >> 4, lrow = lane & 15;
    const int sw = lrow & 7;            // swizzle key for MFMA reads

    // staging geometry: lane -> (row offset 0..7, physical chunk lane&7)
    const int rowoff = lane >> 3;
    const int lchunk = (lane & 7) ^ rowoff;   // logical 16B-chunk this lane fetches

    int py4[4], px4[4], pb4[4], pix4[4];
    #pragma unroll
    for (int q = 0; q < 4; ++q) {
        int r = 32 * wv + 8 * q + rowoff;
        int pix = mbase + r;
        pix4[q] = pix;
        int pb = pix / HW_;
        int pr = pix - pb * HW_;
        py4[q] = pr / 65; px4[q] = pr - py4[q] * 65; pb4[q] = pb;
    }

    f32x4 acc[4][4];
    #pragma unroll
    for (int i = 0; i < 4; ++i)
        #pragma unroll
        for (int j = 0; j < 4; ++j) acc[i][j] = (f32x4){0.f, 0.f, 0.f, 0.f};

    for (int tap = 0; tap < ntaps; ++tap) {
        int dy = (ntaps == 1) ? 0 : (tap / 3 - 1) * dil;
        int dx = (ntaps == 1) ? 0 : (tap % 3 - 1) * dil;

        const unsigned short* aptr[4];
        const unsigned short* bptr[4];
        bool av[4];
        bool anyv = false;
        #pragma unroll
        for (int q = 0; q < 4; ++q) {
            int ys = py4[q] + dy, xs = px4[q] + dx;
            bool v = (pix4[q] < NPIX_) && ((unsigned)ys < 65u) && ((unsigned)xs < 65u);
            av[q] = v; anyv |= v;
            aptr[q] = v ? (xin + ((size_t)(pb4[q] * HW_ + ys * 65 + xs)) * cin + lchunk * 8) : zp;
            bptr[q] = wr_base + ((size_t)((bz * 9 + tap) * 256 + nbase + 32 * wv + 8 * q + rowoff)) * cin + lchunk * 8;
        }

        // block-uniform tap skip (whole tile out of bounds for this tap)
        if (tid == 0) tapvalid = 0;
        __syncthreads();
        if (anyv) tapvalid = 1;
        __syncthreads();
        if (!tapvalid) continue;

        for (int kc = 0; kc < cin; kc += 64) {
            __syncthreads();   // WAR: previous compute's LDS reads done
            #pragma unroll
            for (int q = 0; q < 4; ++q) {
                const unsigned short* pa = av[q] ? (aptr[q] + kc) : zp;
                __builtin_amdgcn_global_load_lds(
                    (const AS1 void*)pa,
                    (AS3 void*)(As + (32 * wv + 8 * q) * 64), 16, 0, 0);
                __builtin_amdgcn_global_load_lds(
                    (const AS1 void*)(bptr[q] + kc),
                    (AS3 void*)(Bs + (32 * wv + 8 * q) * 64), 16, 0, 0);
            }
            __syncthreads();   // RAW: compiler drains vmcnt before barrier

            #pragma unroll
            for (int kk = 0; kk < 2; ++kk) {
                const int koch = kk * 4 + quad;      // logical chunk 0..7
                bf16x8 af[4], bfv[4];
                #pragma unroll
                for (int i = 0; i < 4; ++i) {
                    int row = wm * 64 + i * 16 + lrow;
                    af[i] = *(const bf16x8*)(As + row * 64 + ((koch ^ sw) << 3));
                }
                #pragma unroll
                for (int j = 0; j < 4; ++j) {
                    int row = wn * 64 + j * 16 + lrow;
                    bfv[j] = *(const bf16x8*)(Bs + row * 64 + ((koch ^ sw) << 3));
                }
                #pragma unroll
                for (int i = 0; i < 4; ++i)
                    #pragma unroll
                    for (int j = 0; j < 4; ++j)
                        acc[i][j] = __builtin_amdgcn_mfma_f32_16x16x32_bf16(
                            af[i], bfv[j], acc[i][j], 0, 0, 0);
            }
        }
    }

    #pragma unroll
    for (int i = 0; i < 4; ++i) {
        int prow = mbase + wm * 64 + i * 16 + quad * 4;
        #pragma unroll
        for (int r = 0; r < 4; ++r) {
            int p = prow + r;
            if (p < NPIX_) {
                unsigned short* orow = out + (size_t)p * ostride + coff + nbase + wn * 64 + lrow;
                #pragma unroll
                for (int j = 0; j < 4; ++j) orow[j * 16] = f2bf(acc[i][j][r]);
            }
        }
    }
}

// ---------------- per-channel sum/sumsq over all pixels (atomic partials) ----------------
__global__ void k_stats(const unsigned short* __restrict__ buf, int stride, int coff,
                        float* __restrict__ sums, float* __restrict__ sumsq) {
    int c = blockIdx.y * 256 + threadIdx.x;
    int p0 = blockIdx.x * 130, p1 = p0 + 130;
    float s = 0.f, q = 0.f;
    for (int p = p0; p < p1; ++p) {
        float v = bf2f(buf[(size_t)p * stride + coff + c]);
        s += v; q += v * v;
    }
    atomicAdd(&sums[c], s);
    atomicAdd(&sumsq[c], q);
}

// ---------------- br0: (w_gp @ gp) -> pre-BN (4,256); gp_acc holds raw sums ----------------
__global__ void k_br0mv(const float* __restrict__ gp, const float* __restrict__ wgp,
                        float* __restrict__ pre) {
    __shared__ float red[256];
    int co = blockIdx.x, t = threadIdx.x;
    float s0 = 0, s1 = 0, s2 = 0, s3 = 0;
    for (int ci = t; ci < 2048; ci += 256) {
        float w = wgp[(size_t)co * 2048 + ci];
        s0 += w * gp[ci];        s1 += w * gp[2048 + ci];
        s2 += w * gp[4096 + ci]; s3 += w * gp[6144 + ci];
    }
    #pragma unroll
    for (int b = 0; b < 4; ++b) {
        float s = (b == 0) ? s0 : (b == 1) ? s1 : (b == 2) ? s2 : s3;
        red[t] = s; __syncthreads();
        for (int st = 128; st; st >>= 1) { if (t < st) red[t] += red[t + st]; __syncthreads(); }
        if (t == 0) pre[b * 256 + co] = red[0] * (1.0f / HW_);
        __syncthreads();
    }
}

// ---------------- br0 BN over batch-of-4 + relu ----------------
__global__ void k_br0bn(const float* __restrict__ pre, const float* __restrict__ g,
                        const float* __restrict__ bb, float* __restrict__ post) {
    int t = threadIdx.x;
    float v0 = pre[t], v1 = pre[256 + t], v2 = pre[512 + t], v3 = pre[768 + t];
    float m = 0.25f * (v0 + v1 + v2 + v3);
    float var = 0.25f * (v0 * v0 + v1 * v1 + v2 * v2 + v3 * v3) - m * m;
    float sc = g[t] * rsqrtf(var + EPSF), sh = bb[t] - m * sc;
    post[t]       = fmaxf(v0 * sc + sh, 0.f);
    post[256 + t] = fmaxf(v1 * sc + sh, 0.f);
    post[512 + t] = fmaxf(v2 * sc + sh, 0.f);
    post[768 + t] = fmaxf(v3 * sc + sh, 0.f);
}

// ---------------- normalize ASPP (in-place) + broadcast br0 into channels 0..255 --------
__global__ void k_norm_aspp(unsigned short* __restrict__ buf,
                            const float* __restrict__ sums, const float* __restrict__ sumsq,
                            const float* __restrict__ g1, const float* __restrict__ b1,
                            const float* __restrict__ g2, const float* __restrict__ b2,
                            const float* __restrict__ g3, const float* __restrict__ b3,
                            const float* __restrict__ g4, const float* __restrict__ b4,
                            const float* __restrict__ br0) {
    int cg = blockIdx.y, t = threadIdx.x;
    int p0 = blockIdx.x * 130, p1 = p0 + 130;
    if (cg == 0) {
        for (int p = p0; p < p1; ++p) {
            int b = p / HW_;
            buf[(size_t)p * 1280 + t] = f2bf(br0[b * 256 + t]);
        }
    } else {
        int c = (cg - 1) * 256 + t;
        float m = sums[c] * (1.f / NPIX_);
        float var = sumsq[c] * (1.f / NPIX_) - m * m;
        const float* g  = (cg == 1) ? g1 : (cg == 2) ? g2 : (cg == 3) ? g3 : g4;
        const float* bb = (cg == 1) ? b1 : (cg == 2) ? b2 : (cg == 3) ? b3 : b4;
        float sc = g[t] * rsqrtf(var + EPSF), sh = bb[t] - m * sc;
        for (int p = p0; p < p1; ++p) {
            size_t idx = (size_t)p * 1280 + cg * 256 + t;
            float v = bf2f(buf[idx]) * sc + sh;
            buf[idx] = f2bf(fmaxf(v, 0.f));
        }
    }
}

// ---------------- normalize head (in-place) -> fea ----------------
__global__ void k_norm_head(unsigned short* __restrict__ buf,
                            const float* __restrict__ sums, const float* __restrict__ sumsq,
                            const float* __restrict__ g, const float* __restrict__ bb) {
    int t = threadIdx.x;
    float m = sums[t] * (1.f / NPIX_);
    float var = sumsq[t] * (1.f / NPIX_) - m * m;
    float sc = g[t] * rsqrtf(var + EPSF), sh = bb[t] - m * sc;
    int p0 = blockIdx.x * 130, p1 = p0 + 130;
    for (int p = p0; p < p1; ++p) {
        size_t idx = (size_t)p * 256 + t;
        float v = bf2f(buf[idx]) * sc + sh;
        buf[idx] = f2bf(fmaxf(v, 0.f));
    }
}

// ---------------- final 1x1: res (NCHW into d_out) ----------------
__global__ void k_final(const unsigned short* __restrict__ fea, const float* __restrict__ wfin,
                        const float* __restrict__ bfin, float* __restrict__ outres) {
    int idx = blockIdx.x * 256 + threadIdx.x;
    if (idx >= NPIX_ * NC_) return;
    int p = idx / NC_, k = idx - p * NC_;
    const unsigned short* f = fea + (size_t)p * 256;
    const float* w = wfin + k * 256;
    float acc = 0.f;
    for (int c = 0; c < 256; c += 8) {
        uint4 q = *(const uint4*)(f + c);
        unsigned u0 = q.x, u1 = q.y, u2 = q.z, u3 = q.w;
        acc += bf2f((unsigned short)(u0 & 0xffff)) * w[c + 0];
        acc += bf2f((unsigned short)(u0 >> 16))    * w[c + 1];
        acc += bf2f((unsigned short)(u1 & 0xffff)) * w[c + 2];
        acc += bf2f((unsigned short)(u1 >> 16))    * w[c + 3];
        acc += bf2f((unsigned short)(u2 & 0xffff)) * w[c + 4];
        acc += bf2f((unsigned short)(u2 >> 16))    * w[c + 5];
        acc += bf2f((unsigned short)(u3 & 0xffff)) * w[c + 6];
        acc += bf2f((unsigned short)(u3 >> 16))    * w[c + 7];
    }
    acc += bfin[k];
    int b = p / HW_, yx = p - b * HW_;
    outres[(size_t)(b * NC_ + k) * HW_ + yx] = acc;
}

// ---------------- argmax over classes (first-max) ----------------
__global__ void k_argmax(const float* __restrict__ res, int* __restrict__ pred) {
    int p = blockIdx.x * 256 + threadIdx.x;
    if (p >= NPIX_) return;
    int b = p / HW_, yx = p - b * HW_;
    const float* r = res + (size_t)b * NC_ * HW_ + yx;
    float best = r[0]; int bi = 0;
    #pragma unroll
    for (int k = 1; k < NC_; ++k) {
        float v = r[(size_t)k * HW_];
        if (v > best) { best = v; bi = k; }
    }
    pred[p] = bi;
}

// ---------------- per-class masked sums of fea + counts ----------------
__global__ void k_keysums(const unsigned short* __restrict__ fea, const int* __restrict__ pred,
                          float* __restrict__ sums, float* __restrict__ counts) {
    __shared__ float acc[256 * NC_];
    __shared__ float cnt[NC_];
    int t = threadIdx.x;
    #pragma unroll
    for (int k = 0; k < NC_; ++k) acc[t * NC_ + k] = 0.f;
    if (t < NC_) cnt[t] = 0.f;
    __syncthreads();
    int p0 = blockIdx.x * 130, p1 = p0 + 130;
    for (int p = p0; p < p1; ++p) {
        int k = pred[p];
        float v = bf2f(fea[(size_t)p * 256 + t]);
        acc[t * NC_ + k] += v;
        if (t == 0) cnt[k] += 1.f;
    }
    __syncthreads();
    #pragma unroll
    for (int k = 0; k < NC_; ++k) atomicAdd(&sums[k * 256 + t], acc[t * NC_ + k]);
    if (t < NC_) atomicAdd(&counts[t], cnt[t]);
}

// ---------------- keys: divide by counts, L2-normalize ----------------
__global__ void k_keys(const float* __restrict__ sums, const float* __restrict__ counts,
                       float* __restrict__ keys) {
    __shared__ float red[256];
    int t = threadIdx.x;
    for (int k = 0; k < NC_; ++k) {
        float v = sums[k * 256 + t] / fmaxf(counts[k], 1.f);
        red[t] = v * v; __syncthreads();
        for (int s = 128; s; s >>= 1) { if (t < s) red[t] += red[t + s]; __syncthreads(); }
        float inv = 1.f / fmaxf(sqrtf(red[0]), 1e-12f);
        keys[k * 256 + t] = v * inv;
        __syncthreads();
    }
}

// ---------------- sims: Sexp[k][j] = sum_l exp(a), pos_a for diagonal ----------------
__global__ void k_sims(const float* __restrict__ keys, const float* __restrict__ queues,
                       float* __restrict__ Sexp, float* __restrict__ pos_a) {
    __shared__ float kl[NC_ * 256];
    __shared__ float red[256];
    int t = threadIdx.x;
    int j = blockIdx.x, lc = blockIdx.y;
    #pragma unroll
    for (int k = 0; k < NC_; ++k) kl[k * 256 + t] = keys[k * 256 + t];
    __syncthreads();
    int l = lc * 256 + t;
    bool lv = l < QL_;
    float a[NC_];
    #pragma unroll
    for (int k = 0; k < NC_; ++k) a[k] = 0.f;
    if (lv) {
        const float* q = queues + (size_t)j * 256 * QL_ + l;
        for (int c = 0; c < 256; ++c) {
            float qv = q[(size_t)c * QL_];
            #pragma unroll
            for (int k = 0; k < NC_; ++k) a[k] += kl[k * 256 + c] * qv;
        }
    }
    const float invt = 1.f / (256.f * 0.2f);
    if (lv) pos_a[j * QL_ + l] = a[j] * invt;
    for (int k = 0; k < NC_; ++k) {
        float e = lv ? __expf(a[k] * invt) : 0.f;
        red[t] = e; __syncthreads();
        for (int s = 128; s; s >>= 1) { if (t < s) red[t] += red[t + s]; __syncthreads(); }
        if (t == 0) atomicAdd(&Sexp[k * NC_ + j], red[0]);
        __syncthreads();
    }
}

// ---------------- final loss ----------------
__global__ void k_loss(const float* __restrict__ Sexp, const float* __restrict__ pos_a,
                       const float* __restrict__ counts, float* __restrict__ out_loss) {
    __shared__ float red[256];
    __shared__ float lseneg[NC_];
    int t = threadIdx.x;
    if (t < NC_) {
        float s = 0.f;
        for (int j = 0; j < NC_; ++j) if (j != t) s += Sexp[t * NC_ + j];
        lseneg[t] = logf(s);
    }
    __syncthreads();
    float total = 0.f;
    for (int k = 0; k < NC_; ++k) {
        float L = lseneg[k];
        float s = 0.f;
        for (int l = t; l < QL_; l += 256) {
            float pos = pos_a[k * QL_ + l];
            float m = fmaxf(pos, L);
            s += logf(__expf(pos - m) + __expf(L - m)) + m - pos;
        }
        red[t] = s; __syncthreads();
        for (int st = 128; st; st >>= 1) { if (t < st) red[t] += red[t + st]; __syncthreads(); }
        if (t == 0 && counts[k] > 0.f) total += red[0] * (1.f / QL_);
        __syncthreads();
    }
    if (t == 0) *out_loss = total;
}

extern "C" void kernel_launch(void* const* d_in, const int* in_sizes, int n_in,
                              void* d_out, int out_size, void* d_ws, size_t ws_size,
                              hipStream_t stream) {
    const float* x      = (const float*)d_in[0];
    const float* w_gp   = (const float*)d_in[1];
    const float* g_gp   = (const float*)d_in[2];
    const float* b_gp   = (const float*)d_in[3];
    const float* w_1x1  = (const float*)d_in[4];
    const float* g_1x1  = (const float*)d_in[5];
    const float* b_1x1  = (const float*)d_in[6];
    const float* w_d12  = (const float*)d_in[7];
    const float* g_d12  = (const float*)d_in[8];
    const float* b_d12  = (const float*)d_in[9];
    const float* w_d24  = (const float*)d_in[10];
    const float* g_d24  = (const float*)d_in[11];
    const float* b_d24  = (const float*)d_in[12];
    const float* w_d36  = (const float*)d_in[13];
    const float* g_d36  = (const float*)d_in[14];
    const float* b_d36  = (const float*)d_in[15];
    const float* w_head = (const float*)d_in[16];
    const float* g_head = (const float*)d_in[17];
    const float* b_head = (const float*)d_in[18];
    const float* w_fin  = (const float*)d_in[19];
    const float* b_fin  = (const float*)d_in[20];
    const float* queues = (const float*)d_in[21];

    char* ws = (char*)d_ws;
    size_t off = 0;
    auto alloc = [&](size_t bytes) { void* p = ws + off; off += (bytes + 255) & ~(size_t)255; return p; };

    unsigned short* x_t     = (unsigned short*)alloc((size_t)4 * HW_ * 2048 * 2);
    unsigned short* wr_aspp = (unsigned short*)alloc((size_t)4 * 9 * 256 * 2048 * 2);
    unsigned short* wr_head = (unsigned short*)alloc((size_t)9 * 256 * 1280 * 2);
    unsigned short* aspp    = (unsigned short*)alloc((size_t)NPIX_ * 1280 * 2);
    unsigned short* headb   = (unsigned short*)alloc((size_t)NPIX_ * 256 * 2);
    float* br0pre  = (float*)alloc(1024 * 4);
    float* br0post = (float*)alloc(1024 * 4);
    int*   pred    = (int*)alloc((size_t)NPIX_ * 4);
    float* pos_a   = (float*)alloc((size_t)NC_ * QL_ * 4);
    // zeroed region: zp(64f) | gp(8192) | aspp s/sq(2048) | head s/sq(512) | key_sums(4864) | counts(19) | Sexp(361)
    float* zbase       = (float*)alloc(16060 * 4);
    unsigned short* zp = (unsigned short*)zbase;      // 256B zero page
    float* gp          = zbase + 64;
    float* aspp_sums   = zbase + 8256;
    float* aspp_sumsq  = zbase + 9280;
    float* head_sums   = zbase + 10304;
    float* head_sumsq  = zbase + 10560;
    float* key_sums    = zbase + 10816;
    float* counts      = zbase + 15680;
    float* Sexp        = zbase + 15699;
    (void)ws_size; (void)in_sizes; (void)n_in; (void)out_size;

    float* res  = (float*)d_out;
    float* loss = (float*)d_out + (size_t)NPIX_ * NC_;

    hipMemsetAsync(zbase, 0, 16060 * 4, stream);

    k_transpose_x<<<dim3(67, 32, 4), 256, 0, stream>>>(x, x_t, gp);

    k_wreorder<<<dim3(8, 256, 1), 256, 0, stream>>>(w_1x1, wr_aspp, 2048, 1);
    k_wreorder<<<dim3(8, 256, 9), 256, 0, stream>>>(w_d12, wr_aspp + (size_t)1 * 9 * 256 * 2048, 2048, 9);
    k_wreorder<<<dim3(8, 256, 9), 256, 0, stream>>>(w_d24, wr_aspp + (size_t)2 * 9 * 256 * 2048, 2048, 9);
    k_wreorder<<<dim3(8, 256, 9), 256, 0, stream>>>(w_d36, wr_aspp + (size_t)3 * 9 * 256 * 2048, 2048, 9);
    k_wreorder<<<dim3(5, 256, 9), 256, 0, stream>>>(w_head, wr_head, 1280, 9);

    k_conv_gemm<<<dim3(133, 2, 4), 256, 0, stream>>>(x_t, wr_aspp, aspp, zp, 2048, 1280, 0);

    k_stats<<<dim3(130, 4), 256, 0, stream>>>(aspp, 1280, 256, aspp_sums, aspp_sumsq);
    k_br0mv<<<256, 256, 0, stream>>>(gp, w_gp, br0pre);
    k_br0bn<<<1, 256, 0, stream>>>(br0pre, g_gp, b_gp, br0post);
    k_norm_aspp<<<dim3(130, 5), 256, 0, stream>>>(aspp, aspp_sums, aspp_sumsq,
        g_1x1, b_1x1, g_d12, b_d12, g_d24, b_d24, g_d36, b_d36, br0post);

    k_conv_gemm<<<dim3(133, 2, 1), 256, 0, stream>>>(aspp, wr_head, headb, zp, 1280, 256, 1);
    k_stats<<<dim3(130, 1), 256, 0, stream>>>(headb, 256, 0, head_sums, head_sumsq);
    k_norm_head<<<130, 256, 0, stream>>>(headb, head_sums, head_sumsq, g_head, b_head);

    k_final<<<(NPIX_ * NC_ + 255) / 256, 256, 0, stream>>>(headb, w_fin, b_fin, res);
    k_argmax<<<(NPIX_ + 255) / 256, 256, 0, stream>>>(res, pred);
    k_keysums<<<130, 256, 0, stream>>>(headb, pred, key_sums, counts);
    k_keys<<<1, 256, 0, stream>>>(key_sums, counts, (float*)br0pre);
    k_sims<<<dim3(NC_, 12), 256, 0, stream>>>((float*)br0pre, queues, Sexp, pos_a);
    k_loss<<<1, 256, 0, stream>>>(Sexp, pos_a, counts, loss);
}